// Round 6
// baseline (115.883 us; speedup 1.0000x reference)
//
#include <hip/hip_runtime.h>

#define EPSF 1e-10f

constexpr int B = 32, K = 4, M = 3;
constexpr int NPIX = 256 * 256;
constexpr int BLOCKS_PER_B = 32;                 // 1024 blocks, all co-resident
constexpr int GRID = B * BLOCKS_PER_B;
constexpr int THREADS = 256;
constexpr int WAVES = THREADS / 64;
constexpr int CHUNKS = NPIX / (BLOCKS_PER_B * THREADS * 4);  // 2 iters, 8 px/thread held
constexpr int NVALS = 1 + K + 2 * K * M;         // 29 phase-1 moments
constexpr int NPAR  = 2 * K + 2 * K * M + 1;     // 33: alpha[4],cst[4],mu[12],iv[12],n

// ---- ws layout. ctrl words zeroed by 512B hipMemsetAsync each launch ----
constexpr int OFF_CNT1 = 0;                      // [B] phase-1 arrival counters
constexpr int OFF_FLAG = 32;                     // [B] params-ready flags
constexpr int OFF_CNT2 = 64;                     // [B] LL arrival counters
constexpr int OFF_CNT3 = 96;                     // global done counter
constexpr int CTRL_BYTES = 512;
constexpr int OFF_PART = 128;                    // [GRID][32] phase-1 partials
constexpr int OFF_LLP  = OFF_PART + GRID * 32;   // [GRID]     LL partials
constexpr int OFF_PAR  = OFF_LLP + GRID;         // [B][40]    published params
constexpr int OFF_PERB = OFF_PAR + B * 40;       // [B]        -ll/n per b

#define RX  __ATOMIC_RELAXED
#define SCP __HIP_MEMORY_SCOPE_AGENT
// wave-level: all this wave's outstanding VMEM ops retired at coherence point
#define VM_DRAIN() asm volatile("s_waitcnt vmcnt(0)" ::: "memory")

__device__ __forceinline__ float wave_reduce(float v) {
    #pragma unroll
    for (int off = 32; off > 0; off >>= 1) v += __shfl_down(v, off, 64);
    return v;
}

__global__ __launch_bounds__(THREADS, 4) void fused_kernel(
    const float* __restrict__ pred, const float* __restrict__ xin,
    const int* __restrict__ heart, float* __restrict__ ws,
    float* __restrict__ out) {
    const int b  = blockIdx.x / BLOCKS_PER_B;
    const int cb = blockIdx.x % BLOCKS_PER_B;
    unsigned* ctrl = (unsigned*)ws;

    // register-held pixel data for the LL phase
    float xh[CHUNKS][M][4];
    float mh[CHUNKS][4];

    float nacc = 0.0f;
    float Wk[K] = {};
    float Pa[K][M] = {};
    float Qa[K][M] = {};

    #pragma unroll
    for (int it = 0; it < CHUNKS; ++it) {
        const int p0 = (((cb * CHUNKS + it) * THREADS) + threadIdx.x) * 4;

        const int4 h4 = *(const int4*)(heart + b * NPIX + p0);
        mh[it][0] = (h4.x == 1) ? 1.0f : 0.0f;
        mh[it][1] = (h4.y == 1) ? 1.0f : 0.0f;
        mh[it][2] = (h4.z == 1) ? 1.0f : 0.0f;
        mh[it][3] = (h4.w == 1) ? 1.0f : 0.0f;
        nacc += (mh[it][0] + mh[it][1]) + (mh[it][2] + mh[it][3]);

        #pragma unroll
        for (int m = 0; m < M; ++m) {
            float4 t = *(const float4*)(xin + (b * M + m) * NPIX + p0);
            xh[it][m][0] = t.x; xh[it][m][1] = t.y;
            xh[it][m][2] = t.z; xh[it][m][3] = t.w;
        }

        #pragma unroll
        for (int k = 0; k < K; ++k) {
            float4 pr = *(const float4*)(pred + (b * K + k) * NPIX + p0);
            float pm[4];
            pm[0] = pr.x * mh[it][0]; pm[1] = pr.y * mh[it][1];
            pm[2] = pr.z * mh[it][2]; pm[3] = pr.w * mh[it][3];
            Wk[k] += (pm[0] + pm[1]) + (pm[2] + pm[3]);
            #pragma unroll
            for (int m = 0; m < M; ++m) {
                #pragma unroll
                for (int j = 0; j < 4; ++j) {
                    float px = pm[j] * xh[it][m][j];
                    Pa[k][m] += px;
                    Qa[k][m] += px * xh[it][m][j];
                }
            }
        }
    }

    // pack 29 values, block-reduce (identical order to verified kernels)
    float vals[NVALS];
    vals[0] = nacc;
    #pragma unroll
    for (int k = 0; k < K; ++k) vals[1 + k] = Wk[k];
    #pragma unroll
    for (int k = 0; k < K; ++k)
        #pragma unroll
        for (int m = 0; m < M; ++m) {
            vals[1 + K + k * M + m]         = Pa[k][m];
            vals[1 + K + K * M + k * M + m] = Qa[k][m];
        }

    __shared__ float red[WAVES * NVALS];
    #pragma unroll
    for (int i = 0; i < NVALS; ++i) vals[i] = wave_reduce(vals[i]);
    const int wave = threadIdx.x >> 6;
    if ((threadIdx.x & 63) == 0) {
        #pragma unroll
        for (int i = 0; i < NVALS; ++i) red[wave * NVALS + i] = vals[i];
    }
    __syncthreads();
    // threads 0..28 (all wave 0) publish partials at the coherence point
    if (threadIdx.x < NVALS) {
        float s = red[threadIdx.x];
        #pragma unroll
        for (int w = 1; w < WAVES; ++w) s += red[w * NVALS + threadIdx.x];
        __hip_atomic_store(&ws[OFF_PART + blockIdx.x * 32 + threadIdx.x], s, RX, SCP);
    }

    // ---- per-b last-arriver computes params; siblings wait on ONE relaxed flag ----
    __shared__ int islast;
    if (threadIdx.x == 0) {
        VM_DRAIN();  // wave 0's 29 partial stores retired before the tick
        unsigned old = __hip_atomic_fetch_add(&ctrl[OFF_CNT1 + b], 1u, RX, SCP);
        islast = (old == BLOCKS_PER_B - 1) ? 1 : 0;
    }
    __syncthreads();

    __shared__ float parr[NPAR];
    if (islast) {
        __shared__ float raw[NVALS];
        if (threadIdx.x < NVALS) {
            const float* base = &ws[OFF_PART + (b * BLOCKS_PER_B) * 32 + threadIdx.x];
            float s = 0.0f;
            #pragma unroll
            for (int c = 0; c < BLOCKS_PER_B; ++c)
                s += __hip_atomic_load(base + c * 32, RX, SCP);
            raw[threadIdx.x] = s;
        }
        __syncthreads();
        if (threadIdx.x == 0) {
            const float n = raw[0];
            #pragma unroll
            for (int k = 0; k < K; ++k) {
                const float W = raw[1 + k];
                const float s = W + EPSF;
                parr[k] = W / n;                       // alpha
                float cst = 0.0f;
                #pragma unroll
                for (int m = 0; m < M; ++m) {
                    const float Pv = raw[1 + K + k * M + m];
                    const float Qv = raw[1 + K + K * M + k * M + m];
                    const float muv = Pv / s;
                    const float var = (Qv - 2.0f * muv * Pv + muv * muv * W) / s + EPSF;
                    parr[2 * K + k * M + m]         = muv;        // mu
                    parr[2 * K + K * M + k * M + m] = 0.5f / var; // iv
                    cst -= 0.5f * logf(6.2831853071795864f * var);
                }
                parr[K + k] = cst;
            }
            parr[NPAR - 1] = n;
        }
        __syncthreads();
        // threads 0..32 (all wave 0) publish params
        if (threadIdx.x < NPAR)
            __hip_atomic_store(&ws[OFF_PAR + b * 40 + threadIdx.x], parr[threadIdx.x], RX, SCP);
        if (threadIdx.x == 0) {
            VM_DRAIN();  // param stores retired before flag raise
            __hip_atomic_store(&ctrl[OFF_FLAG + b], 1u, RX, SCP);
        }
    } else {
        if (threadIdx.x == 0) {
            while (__hip_atomic_load(&ctrl[OFF_FLAG + b], RX, SCP) == 0u)
                __builtin_amdgcn_s_sleep(8);
        }
        __syncthreads();   // compiler+wave fence: param loads cannot hoist above
        if (threadIdx.x < NPAR)
            parr[threadIdx.x] = __hip_atomic_load(&ws[OFF_PAR + b * 40 + threadIdx.x], RX, SCP);
        __syncthreads();
    }
    __syncthreads();

    // unpack params (identical floats in every block of this b)
    float alpha[K], cstk[K], mu[K][M], iv[K][M];
    #pragma unroll
    for (int k = 0; k < K; ++k) {
        alpha[k] = parr[k];
        cstk[k]  = parr[K + k];
        #pragma unroll
        for (int m = 0; m < M; ++m) {
            mu[k][m] = parr[2 * K + k * M + m];
            iv[k][m] = parr[2 * K + K * M + k * M + m];
        }
    }

    // ---- LL on register-held pixels: zero global reads ----
    float acc = 0.0f;
    #pragma unroll
    for (int it = 0; it < CHUNKS; ++it) {
        #pragma unroll
        for (int j = 0; j < 4; ++j) {
            float mix = EPSF;
            #pragma unroll
            for (int k = 0; k < K; ++k) {
                float lp = cstk[k];
                #pragma unroll
                for (int m = 0; m < M; ++m) {
                    float d = xh[it][m][j] - mu[k][m];
                    lp -= d * d * iv[k][m];
                }
                mix += alpha[k] * __expf(lp);
            }
            acc += mh[it][j] * __logf(mix);
        }
    }

    __shared__ float red2[WAVES];
    acc = wave_reduce(acc);
    if ((threadIdx.x & 63) == 0) red2[threadIdx.x >> 6] = acc;
    __syncthreads();

    // ---- wait-free finish: relaxed atomics + vmcnt drains (verified round 5) ----
    if (threadIdx.x == 0) {
        float s = red2[0];
        #pragma unroll
        for (int w = 1; w < WAVES; ++w) s += red2[w];
        __hip_atomic_store(&ws[OFF_LLP + blockIdx.x], s, RX, SCP);
        VM_DRAIN();
        unsigned old = __hip_atomic_fetch_add(&ctrl[OFF_CNT2 + b], 1u, RX, SCP);
        if (old == BLOCKS_PER_B - 1) {
            float ll = 0.0f;
            #pragma unroll
            for (int c = 0; c < BLOCKS_PER_B; ++c)
                ll += __hip_atomic_load(&ws[OFF_LLP + b * BLOCKS_PER_B + c], RX, SCP);
            float pb = -ll / parr[NPAR - 1];
            __hip_atomic_store(&ws[OFF_PERB + b], pb, RX, SCP);
            VM_DRAIN();
            unsigned o2 = __hip_atomic_fetch_add(&ctrl[OFF_CNT3], 1u, RX, SCP);
            if (o2 == B - 1) {
                float r = 0.0f;
                #pragma unroll
                for (int bb = 0; bb < B; ++bb)
                    r += __hip_atomic_load(&ws[OFF_PERB + bb], RX, SCP);
                out[0] = r / (float)B;
            }
        }
    }
}

extern "C" void kernel_launch(void* const* d_in, const int* in_sizes, int n_in,
                              void* d_out, int out_size, void* d_ws, size_t ws_size,
                              hipStream_t stream) {
    const float* pred  = (const float*)d_in[0];
    const float* xin   = (const float*)d_in[1];
    const int*   heart = (const int*)d_in[2];
    float* out = (float*)d_out;
    float* ws  = (float*)d_ws;

    hipMemsetAsync(d_ws, 0, CTRL_BYTES, stream);   // zero counters/flags only
    fused_kernel<<<GRID, THREADS, 0, stream>>>(pred, xin, heart, ws, out);
}

// Round 7
// 111.456 us; speedup vs baseline: 1.0397x; 1.0397x over previous
//
#include <hip/hip_runtime.h>

#define EPSF 1e-10f

constexpr int B = 32, K = 4, M = 3;
constexpr int NPIX = 256 * 256;
constexpr int BLOCKS_PER_B = 32;                 // 1024 blocks -> 4 blocks/CU, 16 waves/CU
constexpr int GRID = B * BLOCKS_PER_B;
constexpr int THREADS = 256;
constexpr int WAVES = THREADS / 64;
constexpr int CHUNKS = NPIX / (BLOCKS_PER_B * THREADS * 4);  // 2 iters/thread
constexpr int NVALS = 1 + K + 2 * K * M;         // 29 reduced values in pass1

// ws float layout: deterministic per-block partials (no memset, no atomics)
constexpr int PSTRIDE  = 32;                      // padded stride per block's partials
constexpr int OFF_PART = 0;                       // [GRID][PSTRIDE] pass1 partials
constexpr int OFF_LLP  = OFF_PART + GRID * PSTRIDE; // [GRID] pass2 LL partials

__device__ __forceinline__ float wave_reduce(float v) {
    #pragma unroll
    for (int off = 32; off > 0; off >>= 1) v += __shfl_down(v, off, 64);
    return v;
}

__global__ __launch_bounds__(THREADS) void pass1_kernel(
    const float* __restrict__ pred, const float* __restrict__ xin,
    const int* __restrict__ heart, float* __restrict__ ws) {
    const int b  = blockIdx.x / BLOCKS_PER_B;
    const int cb = blockIdx.x % BLOCKS_PER_B;

    float nacc = 0.0f;
    float Wk[K] = {};
    float Pa[K][M] = {};
    float Qa[K][M] = {};

    #pragma unroll
    for (int it = 0; it < CHUNKS; ++it) {
        const int p0 = (((cb * CHUNKS + it) * THREADS) + threadIdx.x) * 4;

        const int4 h4 = *(const int4*)(heart + b * NPIX + p0);
        float mk[4];
        mk[0] = (h4.x == 1) ? 1.0f : 0.0f;
        mk[1] = (h4.y == 1) ? 1.0f : 0.0f;
        mk[2] = (h4.z == 1) ? 1.0f : 0.0f;
        mk[3] = (h4.w == 1) ? 1.0f : 0.0f;
        nacc += (mk[0] + mk[1]) + (mk[2] + mk[3]);

        float xv[M][4];
        #pragma unroll
        for (int m = 0; m < M; ++m) {
            float4 t = *(const float4*)(xin + (b * M + m) * NPIX + p0);
            xv[m][0] = t.x; xv[m][1] = t.y; xv[m][2] = t.z; xv[m][3] = t.w;
        }

        #pragma unroll
        for (int k = 0; k < K; ++k) {
            float4 pr = *(const float4*)(pred + (b * K + k) * NPIX + p0);
            float pm[4];
            pm[0] = pr.x * mk[0]; pm[1] = pr.y * mk[1];
            pm[2] = pr.z * mk[2]; pm[3] = pr.w * mk[3];
            Wk[k] += (pm[0] + pm[1]) + (pm[2] + pm[3]);
            #pragma unroll
            for (int m = 0; m < M; ++m) {
                #pragma unroll
                for (int j = 0; j < 4; ++j) {
                    float px = pm[j] * xv[m][j];
                    Pa[k][m] += px;
                    Qa[k][m] += px * xv[m][j];
                }
            }
        }
    }

    // pack 29 values
    float vals[NVALS];
    vals[0] = nacc;
    #pragma unroll
    for (int k = 0; k < K; ++k) vals[1 + k] = Wk[k];
    #pragma unroll
    for (int k = 0; k < K; ++k)
        #pragma unroll
        for (int m = 0; m < M; ++m) {
            vals[1 + K + k * M + m]         = Pa[k][m];
            vals[1 + K + K * M + k * M + m] = Qa[k][m];
        }

    // wave reduce -> LDS -> cross-wave reduce -> deterministic per-block store
    __shared__ float red[WAVES * NVALS];
    #pragma unroll
    for (int i = 0; i < NVALS; ++i) vals[i] = wave_reduce(vals[i]);
    const int wave = threadIdx.x >> 6;
    if ((threadIdx.x & 63) == 0) {
        #pragma unroll
        for (int i = 0; i < NVALS; ++i) red[wave * NVALS + i] = vals[i];
    }
    __syncthreads();
    const int i = threadIdx.x;
    if (i < NVALS) {
        float s = red[i];
        #pragma unroll
        for (int w = 1; w < WAVES; ++w) s += red[w * NVALS + i];
        ws[OFF_PART + blockIdx.x * PSTRIDE + i] = s;   // plain store, no atomic
    }
}

__global__ __launch_bounds__(THREADS) void pass2_kernel(
    const float* __restrict__ xin, const int* __restrict__ heart,
    float* __restrict__ ws) {
    const int b  = blockIdx.x / BLOCKS_PER_B;
    const int cb = blockIdx.x % BLOCKS_PER_B;

    // prologue: deterministic sum of this b's 32 partial blocks
    __shared__ float raw[NVALS];
    if (threadIdx.x < NVALS) {
        const float* base = ws + OFF_PART + (b * BLOCKS_PER_B) * PSTRIDE + threadIdx.x;
        float s = 0.0f;
        #pragma unroll
        for (int c = 0; c < BLOCKS_PER_B; ++c) s += base[c * PSTRIDE];
        raw[threadIdx.x] = s;
    }
    __syncthreads();

    // params (same formulas as old params_kernel; computed redundantly per thread)
    float alpha[K], cstk[K], mu[K][M], iv[K][M];
    {
        const float n = raw[0];
        #pragma unroll
        for (int k = 0; k < K; ++k) {
            const float W = raw[1 + k];
            const float s = W + EPSF;
            alpha[k] = W / n;
            float cst = 0.0f;
            #pragma unroll
            for (int m = 0; m < M; ++m) {
                const float Pv = raw[1 + K + k * M + m];
                const float Qv = raw[1 + K + K * M + k * M + m];
                const float muv = Pv / s;
                const float var = (Qv - 2.0f * muv * Pv + muv * muv * W) / s + EPSF;
                mu[k][m] = muv;
                iv[k][m] = 0.5f / var;
                cst -= 0.5f * logf(6.2831853071795864f * var);
            }
            cstk[k] = cst;
        }
    }

    float acc = 0.0f;  // sum of mask * ll
    #pragma unroll
    for (int it = 0; it < CHUNKS; ++it) {
        const int p0 = (((cb * CHUNKS + it) * THREADS) + threadIdx.x) * 4;

        const int4 h4 = *(const int4*)(heart + b * NPIX + p0);
        int hv[4] = {h4.x, h4.y, h4.z, h4.w};

        float xv[M][4];
        #pragma unroll
        for (int m = 0; m < M; ++m) {
            float4 t = *(const float4*)(xin + (b * M + m) * NPIX + p0);
            xv[m][0] = t.x; xv[m][1] = t.y; xv[m][2] = t.z; xv[m][3] = t.w;
        }

        #pragma unroll
        for (int j = 0; j < 4; ++j) {
            float mix = EPSF;
            #pragma unroll
            for (int k = 0; k < K; ++k) {
                float lp = cstk[k];
                #pragma unroll
                for (int m = 0; m < M; ++m) {
                    float d = xv[m][j] - mu[k][m];
                    lp -= d * d * iv[k][m];
                }
                mix += alpha[k] * __expf(lp);
            }
            float mask = (hv[j] == 1) ? 1.0f : 0.0f;
            acc += mask * __logf(mix);
        }
    }

    __shared__ float red2[WAVES];
    acc = wave_reduce(acc);
    if ((threadIdx.x & 63) == 0) red2[threadIdx.x >> 6] = acc;
    __syncthreads();
    if (threadIdx.x == 0) {
        float s = red2[0];
        #pragma unroll
        for (int w = 1; w < WAVES; ++w) s += red2[w];
        ws[OFF_LLP + blockIdx.x] = s;   // plain store, deterministic
    }
}

__global__ void final_kernel(const float* __restrict__ ws, float* __restrict__ out) {
    const int lane = threadIdx.x;   // one wave of 64
    float r = 0.0f;
    if (lane < B) {
        float ll = 0.0f, n = 0.0f;
        #pragma unroll
        for (int c = 0; c < BLOCKS_PER_B; ++c) {
            ll += ws[OFF_LLP + lane * BLOCKS_PER_B + c];
            n  += ws[OFF_PART + (lane * BLOCKS_PER_B + c) * PSTRIDE + 0];
        }
        r = -ll / n;
    }
    r = wave_reduce(r);
    if (lane == 0) out[0] = r / (float)B;
}

extern "C" void kernel_launch(void* const* d_in, const int* in_sizes, int n_in,
                              void* d_out, int out_size, void* d_ws, size_t ws_size,
                              hipStream_t stream) {
    const float* pred  = (const float*)d_in[0];
    const float* xin   = (const float*)d_in[1];
    const int*   heart = (const int*)d_in[2];
    float* out = (float*)d_out;
    float* ws  = (float*)d_ws;

    pass1_kernel<<<GRID, THREADS, 0, stream>>>(pred, xin, heart, ws);
    pass2_kernel<<<GRID, THREADS, 0, stream>>>(xin, heart, ws);
    final_kernel<<<1, 64, 0, stream>>>(ws, out);
}